// Round 14
// baseline (134.092 us; speedup 1.0000x reference)
//
// SimCSE MI355X — R14 (attempt 3 of the 3-blocks/CU experiment; source
// perturbed vs R12/R13 to dodge any source-keyed container cache state).
#include <hip/hip_runtime.h>
#include <hip/hip_bf16.h>

#define NROWS 8192
#define DDIM  256
#define INV_TEMP 20.0f   // 1/0.05

typedef __attribute__((ext_vector_type(8))) short bf16x8;
typedef __attribute__((ext_vector_type(4))) float f32x4;

// async global->LDS, 16B per lane. LDS dest = uniform base (+ lane*16 by HW).
__device__ static inline void async16(const void* g, void* l) {
    __builtin_amdgcn_global_load_lds(
        (const __attribute__((address_space(1))) void*)g,
        (__attribute__((address_space(3))) void*)l, 16, 0, 0);
}

// ---------------------------------------------------------------------------
// Kernel 1: per-row L2-normalize q and p (fp32), emit bf16 copies (linear
// row-major), fp32 diag. One wave per row, 4 rows per block. Block 0 zeroes
// the rowsum ticket (stream-ordered before kernel 3; graph-replay safe).
// ---------------------------------------------------------------------------
__global__ __launch_bounds__(256) void norm_diag_kernel(
    const float* __restrict__ q, const float* __restrict__ p,
    unsigned short* __restrict__ qn, unsigned short* __restrict__ pn,
    float* __restrict__ diag, int* __restrict__ tickets)
{
    if (blockIdx.x == 0 && threadIdx.x == 0) tickets[0] = 0;

    const int row  = (blockIdx.x << 2) + (threadIdx.x >> 6);
    const int lane = threadIdx.x & 63;

    const float4 qv = ((const float4*)(q + (size_t)row * DDIM))[lane];
    const float4 pv = ((const float4*)(p + (size_t)row * DDIM))[lane];

    float sq = qv.x*qv.x + qv.y*qv.y + qv.z*qv.z + qv.w*qv.w;
    float sp = pv.x*pv.x + pv.y*pv.y + pv.z*pv.z + pv.w*pv.w;
    #pragma unroll
    for (int m = 1; m < 64; m <<= 1) {
        sq += __shfl_xor(sq, m);
        sp += __shfl_xor(sp, m);
    }
    const float qs = 1.0f / fmaxf(sqrtf(sq), 1e-8f);
    const float ps = 1.0f / fmaxf(sqrtf(sp), 1e-8f);

    const float qx = qv.x*qs, qy = qv.y*qs, qz = qv.z*qs, qw = qv.w*qs;
    const float px = pv.x*ps, py = pv.y*ps, pz = pv.z*ps, pw = pv.w*ps;

    float d = qx*px + qy*py + qz*pz + qw*pw;
    #pragma unroll
    for (int m = 1; m < 64; m <<= 1) d += __shfl_xor(d, m);
    if (lane == 0) diag[row] = d * INV_TEMP;

    union { unsigned short u16[4]; uint2 v; } uq, up;
    {
        __hip_bfloat16 b;
        b = __float2bfloat16(qx); uq.u16[0] = *(unsigned short*)&b;
        b = __float2bfloat16(qy); uq.u16[1] = *(unsigned short*)&b;
        b = __float2bfloat16(qz); uq.u16[2] = *(unsigned short*)&b;
        b = __float2bfloat16(qw); uq.u16[3] = *(unsigned short*)&b;
        b = __float2bfloat16(px); up.u16[0] = *(unsigned short*)&b;
        b = __float2bfloat16(py); up.u16[1] = *(unsigned short*)&b;
        b = __float2bfloat16(pz); up.u16[2] = *(unsigned short*)&b;
        b = __float2bfloat16(pw); up.u16[3] = *(unsigned short*)&b;
    }
    *(uint2*)(qn + (size_t)row * DDIM + lane * 4) = uq.v;
    *(uint2*)(pn + (size_t)row * DDIM + lane * 4) = up.v;
}

// ---------------------------------------------------------------------------
// Kernel 2: fused GEMM + sum-exp, 256x128 tile, 3 BLOCKS/CU (R11 +1 TLP step).
// R11 confirmed: inter-block TLP covers the lockstep pipeline's stalls
// (65.0 -> 57.1 us going 1->2 blocks/CU). This round: 2 LDS buffers (48 KB)
// -> LDS-capped 3 blocks/CU, 24 waves/CU. With 2 buffers only one stage can
// be in flight, so the end-of-iter wait is a vmcnt(0) drain (minimum
// 2-phase); the stage is issued at iter START so it has ~1 full iter of
// compute to cover its L2-hit latency, plus 24-wave TLP.
// Rotation safety: stage(t+1)->buf[t^1] is issued only after the end-of-t
// barrier; all iter-t ds_reads of buf[t] complete before that barrier
// (explicit lgkmcnt(0)).
// 8 waves (4 row x 2 col), wave tile 64x64: af[4]/bf[4]/acc[4][4], 16
// MFMA/K-step (R11's 64-VGPR per-wave shape, so launch_bounds(512,4)'s
// 128-VGPR slack still yields 3 blocks/CU — LDS is the binding cap).
// Staging: 24 tiles (16 A + 8 B) over 8 waves = 3 per wave.
// ---------------------------------------------------------------------------
__global__ __launch_bounds__(512, 4) void simexp_kernel(
    const unsigned short* __restrict__ qn,
    const unsigned short* __restrict__ pn,
    float* __restrict__ part)       // [64 colblocks][8192 rows]
{
    __shared__ unsigned char lds[2 * 24576];   // 2 x (As 16KB | Bs 8KB)

    const int tid  = threadIdx.x;
    const int lane = tid & 63;
    const int w    = tid >> 6;        // wave 0..7
    const int wr   = w >> 1;          // wave row (0..3): 64 rows each
    const int wc   = w & 1;           // wave col (0..1): 64 cols each
    const int quad = lane >> 4;
    const int l16  = lane & 15;
    const int loff = lane * 16;       // = quad*256 + l16*16

    // ---- XCD-chunked swizzle (bijective on 2048 blocks) ----
    const int L   = blockIdx.x;
    const int xcd = L & 7;
    const int c   = L >> 3;                    // 0..255
    const int rowblk = xcd * 4 + (c & 3);      // 32 rowblocks of 256 rows
    const int colblk = c >> 2;                 // 64 colblocks of 128 cols
    const int rowbase = rowblk * 256;
    const int colbase = colblk * 128;

    // staging: 24 16-row tiles per K-step (A: 0..15, B: 16..23); wave w owns
    // tiles {3w, 3w+1, 3w+2}. lane l -> row (l&15), 16B chunk (l>>4).
    const unsigned short* gsrc0; const unsigned short* gsrc1;
    const unsigned short* gsrc2;
    int ldst0, ldst1, ldst2;
    {
        const int i0 = 3*w, i1 = 3*w + 1, i2 = 3*w + 2;
        gsrc0 = (i0 < 16) ? qn + (size_t)(rowbase + i0*16 + l16) * DDIM + quad * 8
                          : pn + (size_t)(colbase + (i0-16)*16 + l16) * DDIM + quad * 8;
        ldst0 = (i0 < 16) ? i0 * 1024 : 16384 + (i0-16) * 1024;
        gsrc1 = (i1 < 16) ? qn + (size_t)(rowbase + i1*16 + l16) * DDIM + quad * 8
                          : pn + (size_t)(colbase + (i1-16)*16 + l16) * DDIM + quad * 8;
        ldst1 = (i1 < 16) ? i1 * 1024 : 16384 + (i1-16) * 1024;
        gsrc2 = (i2 < 16) ? qn + (size_t)(rowbase + i2*16 + l16) * DDIM + quad * 8
                          : pn + (size_t)(colbase + (i2-16)*16 + l16) * DDIM + quad * 8;
        ldst2 = (i2 < 16) ? i2 * 1024 : 16384 + (i2-16) * 1024;
    }

    f32x4 acc[4][4];
    #pragma unroll
    for (int i = 0; i < 4; ++i)
        #pragma unroll
        for (int j = 0; j < 4; ++j) acc[i][j] = (f32x4)0.0f;

#define STAGE(buf, ks) do {                                             \
        unsigned char* _b = lds + (buf) * 24576;                        \
        async16(gsrc0 + (ks) * 32, _b + ldst0);                         \
        async16(gsrc1 + (ks) * 32, _b + ldst1);                         \
        async16(gsrc2 + (ks) * 32, _b + ldst2);                         \
    } while (0)

    STAGE(0, 0);
    asm volatile("s_waitcnt vmcnt(0)" ::: "memory");   // stage(0) landed
    __builtin_amdgcn_s_barrier();
    asm volatile("" ::: "memory");

    #pragma unroll
    for (int ks = 0; ks < 8; ++ks) {
        if (ks < 7) STAGE((ks + 1) & 1, ks + 1);       // issue next-iter stage

        const unsigned char* ba = lds + (ks & 1) * 24576;
        bf16x8 af[4], bf[4];
        #pragma unroll
        for (int i = 0; i < 4; ++i)
            af[i] = *(const bf16x8*)(ba + (wr*4 + i) * 1024 + loff);
        #pragma unroll
        for (int j = 0; j < 4; ++j)
            bf[j] = *(const bf16x8*)(ba + 16384 + (wc*4 + j) * 1024 + loff);

        #pragma unroll
        for (int i = 0; i < 4; ++i)
            #pragma unroll
            for (int j = 0; j < 4; ++j)
                acc[i][j] = __builtin_amdgcn_mfma_f32_16x16x32_bf16(
                    af[i], bf[j], acc[i][j], 0, 0, 0);

        if (ks < 7) {
            // next stage landed + this iter's ds_reads drained, then barrier
            asm volatile("s_waitcnt vmcnt(0) lgkmcnt(0)" ::: "memory");
            __builtin_amdgcn_s_barrier();
            asm volatile("" ::: "memory");
        }
    }
#undef STAGE

    // epilogue ------------------------------------------------------------
    __syncthreads();                   // all ds_reads done; reuse LDS
    float* red = (float*)lds;          // 2 x 256 floats: [wc][256 rows]

    #pragma unroll
    for (int i = 0; i < 4; ++i)
        #pragma unroll
        for (int r = 0; r < 4; ++r) {
            float s = __expf(acc[i][0][r] * INV_TEMP)
                    + __expf(acc[i][1][r] * INV_TEMP)
                    + __expf(acc[i][2][r] * INV_TEMP)
                    + __expf(acc[i][3][r] * INV_TEMP);
            s += __shfl_xor(s, 1);
            s += __shfl_xor(s, 2);
            s += __shfl_xor(s, 4);
            s += __shfl_xor(s, 8);
            if (l16 == 0)
                red[wc * 256 + wr * 64 + i * 16 + quad * 4 + r] = s;
        }
    __syncthreads();

    if (tid < 256)
        part[(size_t)colblk * NROWS + rowbase + tid] = red[tid] + red[256 + tid];
}

// ---------------------------------------------------------------------------
// Kernel 3: per-row total + log - diag, block partials, fused final mean via
// a 64-block completion ticket (64 agent-scope RMWs, us-scale — R6-proven).
// ---------------------------------------------------------------------------
__global__ __launch_bounds__(128) void rowsum_final_kernel(
    const float* __restrict__ part, const float* __restrict__ diag,
    float* __restrict__ loss_part, int* __restrict__ tickets,
    float* __restrict__ out)
{
    const int row = blockIdx.x * 128 + threadIdx.x;
    float s = 0.0f;
    #pragma unroll 4
    for (int cb = 0; cb < 64; ++cb)
        s += part[(size_t)cb * NROWS + row];     // coalesced across threads
    float v = logf(s) - diag[row];

    #pragma unroll
    for (int m = 1; m < 64; m <<= 1) v += __shfl_xor(v, m);
    __shared__ float wsum[2];
    __shared__ int swin;
    if ((threadIdx.x & 63) == 0) wsum[threadIdx.x >> 6] = v;
    __syncthreads();
    if (threadIdx.x == 0) {
        __hip_atomic_store(&loss_part[blockIdx.x], wsum[0] + wsum[1],
            __ATOMIC_RELEASE, __HIP_MEMORY_SCOPE_AGENT);
        swin = __hip_atomic_fetch_add(&tickets[0], 1,
                   __ATOMIC_ACQ_REL, __HIP_MEMORY_SCOPE_AGENT);
    }
    __syncthreads();
    if (swin != 63) return;            // not the last block

    if (threadIdx.x < 64) {
        float x = __hip_atomic_load(&loss_part[threadIdx.x],
                      __ATOMIC_RELAXED, __HIP_MEMORY_SCOPE_AGENT);
        #pragma unroll
        for (int m = 1; m < 64; m <<= 1) x += __shfl_xor(x, m);
        if (threadIdx.x == 0) out[0] = x * (1.0f / NROWS);
    }
}

// ---------------------------------------------------------------------------
extern "C" void kernel_launch(void* const* d_in, const int* in_sizes, int n_in,
                              void* d_out, int out_size, void* d_ws, size_t ws_size,
                              hipStream_t stream)
{
    const float* q = (const float*)d_in[0];
    const float* p = (const float*)d_in[1];

    char* ws = (char*)d_ws;
    unsigned short* qn   = (unsigned short*)ws;                          // 4 MB
    unsigned short* pn   = (unsigned short*)(ws + (size_t)NROWS*DDIM*2); // 4 MB
    float* part      = (float*)(ws + 2*(size_t)NROWS*DDIM*2);            // 2 MB
    float* diag      = part + 64 * (size_t)NROWS;                        // 32 KB
    float* loss_part = diag + NROWS;                                     // 256 B
    int*   tickets   = (int*)(loss_part + 64);

    norm_diag_kernel<<<NROWS/4, 256, 0, stream>>>(q, p, qn, pn, diag, tickets);

    simexp_kernel<<<2048, 512, 0, stream>>>(qn, pn, part);

    rowsum_final_kernel<<<64, 128, 0, stream>>>(part, diag, loss_part,
                                                tickets, (float*)d_out);
}

// Round 15
// 125.872 us; speedup vs baseline: 1.0653x; 1.0653x over previous
//
#include <hip/hip_runtime.h>
#include <hip/hip_bf16.h>

#define NROWS 8192
#define DDIM  256
#define INV_TEMP 20.0f   // 1/0.05

typedef __attribute__((ext_vector_type(8))) short bf16x8;
typedef __attribute__((ext_vector_type(4))) float f32x4;

// async global->LDS, 16B per lane. LDS dest = uniform base (+ lane*16 by HW).
__device__ static inline void async16(const void* g, void* l) {
    __builtin_amdgcn_global_load_lds(
        (const __attribute__((address_space(1))) void*)g,
        (__attribute__((address_space(3))) void*)l, 16, 0, 0);
}

// ---------------------------------------------------------------------------
// Kernel 1: per-row L2-normalize q and p (fp32), emit bf16 copies (linear
// row-major), fp32 diag. One wave per row, 4 rows per block. Block 0 zeroes
// the rowsum ticket (stream-ordered before kernel 3; graph-replay safe).
// ---------------------------------------------------------------------------
__global__ __launch_bounds__(256) void norm_diag_kernel(
    const float* __restrict__ q, const float* __restrict__ p,
    unsigned short* __restrict__ qn, unsigned short* __restrict__ pn,
    float* __restrict__ diag, int* __restrict__ tickets)
{
    if (blockIdx.x == 0 && threadIdx.x == 0) tickets[0] = 0;

    const int row  = (blockIdx.x << 2) + (threadIdx.x >> 6);
    const int lane = threadIdx.x & 63;

    const float4 qv = ((const float4*)(q + (size_t)row * DDIM))[lane];
    const float4 pv = ((const float4*)(p + (size_t)row * DDIM))[lane];

    float sq = qv.x*qv.x + qv.y*qv.y + qv.z*qv.z + qv.w*qv.w;
    float sp = pv.x*pv.x + pv.y*pv.y + pv.z*pv.z + pv.w*pv.w;
    #pragma unroll
    for (int m = 1; m < 64; m <<= 1) {
        sq += __shfl_xor(sq, m);
        sp += __shfl_xor(sp, m);
    }
    const float qs = 1.0f / fmaxf(sqrtf(sq), 1e-8f);
    const float ps = 1.0f / fmaxf(sqrtf(sp), 1e-8f);

    const float qx = qv.x*qs, qy = qv.y*qs, qz = qv.z*qs, qw = qv.w*qs;
    const float px = pv.x*ps, py = pv.y*ps, pz = pv.z*ps, pw = pv.w*ps;

    float d = qx*px + qy*py + qz*pz + qw*pw;
    #pragma unroll
    for (int m = 1; m < 64; m <<= 1) d += __shfl_xor(d, m);
    if (lane == 0) diag[row] = d * INV_TEMP;

    union { unsigned short u16[4]; uint2 v; } uq, up;
    {
        __hip_bfloat16 b;
        b = __float2bfloat16(qx); uq.u16[0] = *(unsigned short*)&b;
        b = __float2bfloat16(qy); uq.u16[1] = *(unsigned short*)&b;
        b = __float2bfloat16(qz); uq.u16[2] = *(unsigned short*)&b;
        b = __float2bfloat16(qw); uq.u16[3] = *(unsigned short*)&b;
        b = __float2bfloat16(px); up.u16[0] = *(unsigned short*)&b;
        b = __float2bfloat16(py); up.u16[1] = *(unsigned short*)&b;
        b = __float2bfloat16(pz); up.u16[2] = *(unsigned short*)&b;
        b = __float2bfloat16(pw); up.u16[3] = *(unsigned short*)&b;
    }
    *(uint2*)(qn + (size_t)row * DDIM + lane * 4) = uq.v;
    *(uint2*)(pn + (size_t)row * DDIM + lane * 4) = up.v;
}

// ---------------------------------------------------------------------------
// Kernel 2: fused GEMM + sum-exp — R11 structure (measured best: simexp 57.1,
// total 125.0) + T5 setprio around the MFMA cluster.
// 256x128 tile, 8 waves (4 row x 2 col), wave tile 64x64, BK=32 x 8.
// 3 LDS buffers (24 KB each: A 16K | B 8K) = 72 KB -> 2 blocks/CU, 16
// waves/CU; depth-2 prefetch with counted vmcnt(3) (never 0 mid-loop).
// R11/R14 A/B established: latency cover needs BOTH in-flight prefetch
// depth AND co-resident blocks (depth-2@2blk = 57.1; depth-1@3blk = 67.0).
// setprio rationale (T5, m191): with 2 independent blocks/CU at different
// pipeline phases, biasing the SIMD scheduler toward the MFMA-holding wave
// while the other block's waves stage/wait is the measured-positive case
// (lockstep single-block was the null case, m190).
// ---------------------------------------------------------------------------
__global__ __launch_bounds__(512, 4) void simexp_kernel(
    const unsigned short* __restrict__ qn,
    const unsigned short* __restrict__ pn,
    float* __restrict__ part)       // [64 colblocks][8192 rows]
{
    __shared__ unsigned char lds[3 * 24576];   // 3 x (As 16KB | Bs 8KB)

    const int tid  = threadIdx.x;
    const int lane = tid & 63;
    const int w    = tid >> 6;        // wave 0..7
    const int wr   = w >> 1;          // wave row (0..3): 64 rows each
    const int wc   = w & 1;           // wave col (0..1): 64 cols each
    const int quad = lane >> 4;
    const int l16  = lane & 15;
    const int loff = lane * 16;       // = quad*256 + l16*16

    // ---- XCD-chunked swizzle (bijective on 2048 blocks) ----
    const int L   = blockIdx.x;
    const int xcd = L & 7;
    const int c   = L >> 3;                    // 0..255
    const int rowblk = xcd * 4 + (c & 3);      // 32 rowblocks of 256 rows
    const int colblk = c >> 2;                 // 64 colblocks of 128 cols
    const int rowbase = rowblk * 256;
    const int colbase = colblk * 128;

    // staging: 24 16-row tiles per K-step (A: 0..15, B: 16..23); wave w owns
    // tiles {3w, 3w+1, 3w+2}. lane l -> row (l&15), 16B chunk (l>>4).
    const unsigned short* gsrc0; const unsigned short* gsrc1;
    const unsigned short* gsrc2;
    int ldst0, ldst1, ldst2;
    {
        const int i0 = 3*w, i1 = 3*w + 1, i2 = 3*w + 2;
        gsrc0 = (i0 < 16) ? qn + (size_t)(rowbase + i0*16 + l16) * DDIM + quad * 8
                          : pn + (size_t)(colbase + (i0-16)*16 + l16) * DDIM + quad * 8;
        ldst0 = (i0 < 16) ? i0 * 1024 : 16384 + (i0-16) * 1024;
        gsrc1 = (i1 < 16) ? qn + (size_t)(rowbase + i1*16 + l16) * DDIM + quad * 8
                          : pn + (size_t)(colbase + (i1-16)*16 + l16) * DDIM + quad * 8;
        ldst1 = (i1 < 16) ? i1 * 1024 : 16384 + (i1-16) * 1024;
        gsrc2 = (i2 < 16) ? qn + (size_t)(rowbase + i2*16 + l16) * DDIM + quad * 8
                          : pn + (size_t)(colbase + (i2-16)*16 + l16) * DDIM + quad * 8;
        ldst2 = (i2 < 16) ? i2 * 1024 : 16384 + (i2-16) * 1024;
    }

    f32x4 acc[4][4];
    #pragma unroll
    for (int i = 0; i < 4; ++i)
        #pragma unroll
        for (int j = 0; j < 4; ++j) acc[i][j] = (f32x4)0.0f;

    // 3 async16 per wave per STAGE -> vmcnt granularity of 3.
#define STAGE(buf, ks) do {                                             \
        unsigned char* _b = lds + (buf) * 24576;                        \
        async16(gsrc0 + (ks) * 32, _b + ldst0);                         \
        async16(gsrc1 + (ks) * 32, _b + ldst1);                         \
        async16(gsrc2 + (ks) * 32, _b + ldst2);                         \
    } while (0)

    STAGE(0, 0);
    STAGE(1, 1);
    asm volatile("s_waitcnt vmcnt(3)" ::: "memory");   // stage(0) landed
    __builtin_amdgcn_s_barrier();
    asm volatile("" ::: "memory");

    #pragma unroll
    for (int ks = 0; ks < 8; ++ks) {
        if (ks < 6) STAGE((ks + 2) % 3, ks + 2);       // issue 2 tiles ahead

        const unsigned char* ba = lds + (ks % 3) * 24576;
        bf16x8 af[4], bf[4];
        #pragma unroll
        for (int i = 0; i < 4; ++i)
            af[i] = *(const bf16x8*)(ba + (wr*4 + i) * 1024 + loff);
        #pragma unroll
        for (int j = 0; j < 4; ++j)
            bf[j] = *(const bf16x8*)(ba + 16384 + (wc*4 + j) * 1024 + loff);

        __builtin_amdgcn_s_setprio(1);                 // T5: favor MFMA wave
        #pragma unroll
        for (int i = 0; i < 4; ++i)
            #pragma unroll
            for (int j = 0; j < 4; ++j)
                acc[i][j] = __builtin_amdgcn_mfma_f32_16x16x32_bf16(
                    af[i], bf[j], acc[i][j], 0, 0, 0);
        __builtin_amdgcn_s_setprio(0);

        if (ks < 7) {
            if (ks < 6) { asm volatile("s_waitcnt vmcnt(3)" ::: "memory"); } // stage(ks+1) done
            else        { asm volatile("s_waitcnt vmcnt(0)" ::: "memory"); } // stage(7) done
            __builtin_amdgcn_s_barrier();
            asm volatile("" ::: "memory");
        }
    }
#undef STAGE

    // epilogue ------------------------------------------------------------
    __syncthreads();                   // all ds_reads done; reuse LDS
    float* red = (float*)lds;          // 2 x 256 floats: [wc][256 rows]

    #pragma unroll
    for (int i = 0; i < 4; ++i)
        #pragma unroll
        for (int r = 0; r < 4; ++r) {
            float s = __expf(acc[i][0][r] * INV_TEMP)
                    + __expf(acc[i][1][r] * INV_TEMP)
                    + __expf(acc[i][2][r] * INV_TEMP)
                    + __expf(acc[i][3][r] * INV_TEMP);
            s += __shfl_xor(s, 1);
            s += __shfl_xor(s, 2);
            s += __shfl_xor(s, 4);
            s += __shfl_xor(s, 8);
            if (l16 == 0)
                red[wc * 256 + wr * 64 + i * 16 + quad * 4 + r] = s;
        }
    __syncthreads();

    if (tid < 256)
        part[(size_t)colblk * NROWS + rowbase + tid] = red[tid] + red[256 + tid];
}

// ---------------------------------------------------------------------------
// Kernel 3: per-row total + log - diag, block partials, fused final mean via
// a 64-block completion ticket (64 agent-scope RMWs, us-scale — R6-proven).
// ---------------------------------------------------------------------------
__global__ __launch_bounds__(128) void rowsum_final_kernel(
    const float* __restrict__ part, const float* __restrict__ diag,
    float* __restrict__ loss_part, int* __restrict__ tickets,
    float* __restrict__ out)
{
    const int row = blockIdx.x * 128 + threadIdx.x;
    float s = 0.0f;
    #pragma unroll 4
    for (int cb = 0; cb < 64; ++cb)
        s += part[(size_t)cb * NROWS + row];     // coalesced across threads
    float v = logf(s) - diag[row];

    #pragma unroll
    for (int m = 1; m < 64; m <<= 1) v += __shfl_xor(v, m);
    __shared__ float wsum[2];
    __shared__ int swin;
    if ((threadIdx.x & 63) == 0) wsum[threadIdx.x >> 6] = v;
    __syncthreads();
    if (threadIdx.x == 0) {
        __hip_atomic_store(&loss_part[blockIdx.x], wsum[0] + wsum[1],
            __ATOMIC_RELEASE, __HIP_MEMORY_SCOPE_AGENT);
        swin = __hip_atomic_fetch_add(&tickets[0], 1,
                   __ATOMIC_ACQ_REL, __HIP_MEMORY_SCOPE_AGENT);
    }
    __syncthreads();
    if (swin != 63) return;            // not the last block

    if (threadIdx.x < 64) {
        float x = __hip_atomic_load(&loss_part[threadIdx.x],
                      __ATOMIC_RELAXED, __HIP_MEMORY_SCOPE_AGENT);
        #pragma unroll
        for (int m = 1; m < 64; m <<= 1) x += __shfl_xor(x, m);
        if (threadIdx.x == 0) out[0] = x * (1.0f / NROWS);
    }
}

// ---------------------------------------------------------------------------
extern "C" void kernel_launch(void* const* d_in, const int* in_sizes, int n_in,
                              void* d_out, int out_size, void* d_ws, size_t ws_size,
                              hipStream_t stream)
{
    const float* q = (const float*)d_in[0];
    const float* p = (const float*)d_in[1];

    char* ws = (char*)d_ws;
    unsigned short* qn   = (unsigned short*)ws;                          // 4 MB
    unsigned short* pn   = (unsigned short*)(ws + (size_t)NROWS*DDIM*2); // 4 MB
    float* part      = (float*)(ws + 2*(size_t)NROWS*DDIM*2);            // 2 MB
    float* diag      = part + 64 * (size_t)NROWS;                        // 32 KB
    float* loss_part = diag + NROWS;                                     // 256 B
    int*   tickets   = (int*)(loss_part + 64);

    norm_diag_kernel<<<NROWS/4, 256, 0, stream>>>(q, p, qn, pn, diag, tickets);

    simexp_kernel<<<2048, 512, 0, stream>>>(qn, pn, part);

    rowsum_final_kernel<<<64, 128, 0, stream>>>(part, diag, loss_part,
                                                tickets, (float*)d_out);
}

// Round 16
// 123.314 us; speedup vs baseline: 1.0874x; 1.0207x over previous
//
#include <hip/hip_runtime.h>
#include <hip/hip_bf16.h>

#define NROWS 8192
#define DDIM  256
#define INV_TEMP 20.0f   // 1/0.05

typedef __attribute__((ext_vector_type(8))) short bf16x8;
typedef __attribute__((ext_vector_type(4))) float f32x4;

// async global->LDS, 16B per lane. LDS dest = uniform base (+ lane*16 by HW).
__device__ static inline void async16(const void* g, void* l) {
    __builtin_amdgcn_global_load_lds(
        (const __attribute__((address_space(1))) void*)g,
        (__attribute__((address_space(3))) void*)l, 16, 0, 0);
}

// ---------------------------------------------------------------------------
// Kernel 1: per-row L2-normalize q and p (fp32), emit bf16 copies (linear
// row-major), fp32 diag. One wave per row, 4 rows per block. Block 0 zeroes
// the rowsum ticket (stream-ordered before kernel 3; graph-replay safe).
// ---------------------------------------------------------------------------
__global__ __launch_bounds__(256) void norm_diag_kernel(
    const float* __restrict__ q, const float* __restrict__ p,
    unsigned short* __restrict__ qn, unsigned short* __restrict__ pn,
    float* __restrict__ diag, int* __restrict__ tickets)
{
    if (blockIdx.x == 0 && threadIdx.x == 0) tickets[0] = 0;

    const int row  = (blockIdx.x << 2) + (threadIdx.x >> 6);
    const int lane = threadIdx.x & 63;

    const float4 qv = ((const float4*)(q + (size_t)row * DDIM))[lane];
    const float4 pv = ((const float4*)(p + (size_t)row * DDIM))[lane];

    float sq = qv.x*qv.x + qv.y*qv.y + qv.z*qv.z + qv.w*qv.w;
    float sp = pv.x*pv.x + pv.y*pv.y + pv.z*pv.z + pv.w*pv.w;
    #pragma unroll
    for (int m = 1; m < 64; m <<= 1) {
        sq += __shfl_xor(sq, m);
        sp += __shfl_xor(sp, m);
    }
    const float qs = 1.0f / fmaxf(sqrtf(sq), 1e-8f);
    const float ps = 1.0f / fmaxf(sqrtf(sp), 1e-8f);

    const float qx = qv.x*qs, qy = qv.y*qs, qz = qv.z*qs, qw = qv.w*qs;
    const float px = pv.x*ps, py = pv.y*ps, pz = pv.z*ps, pw = pv.w*ps;

    float d = qx*px + qy*py + qz*pz + qw*pw;
    #pragma unroll
    for (int m = 1; m < 64; m <<= 1) d += __shfl_xor(d, m);
    if (lane == 0) diag[row] = d * INV_TEMP;

    union { unsigned short u16[4]; uint2 v; } uq, up;
    {
        __hip_bfloat16 b;
        b = __float2bfloat16(qx); uq.u16[0] = *(unsigned short*)&b;
        b = __float2bfloat16(qy); uq.u16[1] = *(unsigned short*)&b;
        b = __float2bfloat16(qz); uq.u16[2] = *(unsigned short*)&b;
        b = __float2bfloat16(qw); uq.u16[3] = *(unsigned short*)&b;
        b = __float2bfloat16(px); up.u16[0] = *(unsigned short*)&b;
        b = __float2bfloat16(py); up.u16[1] = *(unsigned short*)&b;
        b = __float2bfloat16(pz); up.u16[2] = *(unsigned short*)&b;
        b = __float2bfloat16(pw); up.u16[3] = *(unsigned short*)&b;
    }
    *(uint2*)(qn + (size_t)row * DDIM + lane * 4) = uq.v;
    *(uint2*)(pn + (size_t)row * DDIM + lane * 4) = up.v;
}

// ---------------------------------------------------------------------------
// Kernel 2: fused GEMM + sum-exp — FINAL (R11 structure, session best:
// simexp 57.1 us, total 125.0 us vs 147.2 baseline).
// 256x128 tile, 8 waves (4 row x 2 col), wave tile 64x64, BK=32 x 8.
// 3 LDS buffers (24 KB each: A 16K | B 8K) = 72 KB -> 2 blocks/CU, 16
// waves/CU; depth-2 prefetch with counted vmcnt(3) (never 0 mid-loop).
// Session-established facts:
//  - latency cover needs BOTH prefetch depth AND co-resident blocks
//    (depth2@2blk=57.1 / depth2@1blk=65.0 / depth1@3blk=67.0);
//  - schedule micro-structure beyond this is null (8-phase, packed-direct,
//    barrier-free, setprio: all 57-69);
//  - 32x32 MFMA regresses (96 us: 8 dependent acc chains expose latency);
//  - in-kernel grid sync in ANY form is catastrophic on this chip
//    (tickets@4096: +330us, cooperative+fence: +290us, spread tickets: +145us).
// ---------------------------------------------------------------------------
__global__ __launch_bounds__(512, 4) void simexp_kernel(
    const unsigned short* __restrict__ qn,
    const unsigned short* __restrict__ pn,
    float* __restrict__ part)       // [64 colblocks][8192 rows]
{
    __shared__ unsigned char lds[3 * 24576];   // 3 x (As 16KB | Bs 8KB)

    const int tid  = threadIdx.x;
    const int lane = tid & 63;
    const int w    = tid >> 6;        // wave 0..7
    const int wr   = w >> 1;          // wave row (0..3): 64 rows each
    const int wc   = w & 1;           // wave col (0..1): 64 cols each
    const int quad = lane >> 4;
    const int l16  = lane & 15;
    const int loff = lane * 16;       // = quad*256 + l16*16

    // ---- XCD-chunked swizzle (bijective on 2048 blocks) ----
    const int L   = blockIdx.x;
    const int xcd = L & 7;
    const int c   = L >> 3;                    // 0..255
    const int rowblk = xcd * 4 + (c & 3);      // 32 rowblocks of 256 rows
    const int colblk = c >> 2;                 // 64 colblocks of 128 cols
    const int rowbase = rowblk * 256;
    const int colbase = colblk * 128;

    // staging: 24 16-row tiles per K-step (A: 0..15, B: 16..23); wave w owns
    // tiles {3w, 3w+1, 3w+2}. lane l -> row (l&15), 16B chunk (l>>4).
    const unsigned short* gsrc0; const unsigned short* gsrc1;
    const unsigned short* gsrc2;
    int ldst0, ldst1, ldst2;
    {
        const int i0 = 3*w, i1 = 3*w + 1, i2 = 3*w + 2;
        gsrc0 = (i0 < 16) ? qn + (size_t)(rowbase + i0*16 + l16) * DDIM + quad * 8
                          : pn + (size_t)(colbase + (i0-16)*16 + l16) * DDIM + quad * 8;
        ldst0 = (i0 < 16) ? i0 * 1024 : 16384 + (i0-16) * 1024;
        gsrc1 = (i1 < 16) ? qn + (size_t)(rowbase + i1*16 + l16) * DDIM + quad * 8
                          : pn + (size_t)(colbase + (i1-16)*16 + l16) * DDIM + quad * 8;
        ldst1 = (i1 < 16) ? i1 * 1024 : 16384 + (i1-16) * 1024;
        gsrc2 = (i2 < 16) ? qn + (size_t)(rowbase + i2*16 + l16) * DDIM + quad * 8
                          : pn + (size_t)(colbase + (i2-16)*16 + l16) * DDIM + quad * 8;
        ldst2 = (i2 < 16) ? i2 * 1024 : 16384 + (i2-16) * 1024;
    }

    f32x4 acc[4][4];
    #pragma unroll
    for (int i = 0; i < 4; ++i)
        #pragma unroll
        for (int j = 0; j < 4; ++j) acc[i][j] = (f32x4)0.0f;

    // 3 async16 per wave per STAGE -> vmcnt granularity of 3.
#define STAGE(buf, ks) do {                                             \
        unsigned char* _b = lds + (buf) * 24576;                        \
        async16(gsrc0 + (ks) * 32, _b + ldst0);                         \
        async16(gsrc1 + (ks) * 32, _b + ldst1);                         \
        async16(gsrc2 + (ks) * 32, _b + ldst2);                         \
    } while (0)

    STAGE(0, 0);
    STAGE(1, 1);
    asm volatile("s_waitcnt vmcnt(3)" ::: "memory");   // stage(0) landed
    __builtin_amdgcn_s_barrier();
    asm volatile("" ::: "memory");

    #pragma unroll
    for (int ks = 0; ks < 8; ++ks) {
        if (ks < 6) STAGE((ks + 2) % 3, ks + 2);       // issue 2 tiles ahead

        const unsigned char* ba = lds + (ks % 3) * 24576;
        bf16x8 af[4], bf[4];
        #pragma unroll
        for (int i = 0; i < 4; ++i)
            af[i] = *(const bf16x8*)(ba + (wr*4 + i) * 1024 + loff);
        #pragma unroll
        for (int j = 0; j < 4; ++j)
            bf[j] = *(const bf16x8*)(ba + 16384 + (wc*4 + j) * 1024 + loff);

        #pragma unroll
        for (int i = 0; i < 4; ++i)
            #pragma unroll
            for (int j = 0; j < 4; ++j)
                acc[i][j] = __builtin_amdgcn_mfma_f32_16x16x32_bf16(
                    af[i], bf[j], acc[i][j], 0, 0, 0);

        if (ks < 7) {
            if (ks < 6) { asm volatile("s_waitcnt vmcnt(3)" ::: "memory"); } // stage(ks+1) done
            else        { asm volatile("s_waitcnt vmcnt(0)" ::: "memory"); } // stage(7) done
            __builtin_amdgcn_s_barrier();
            asm volatile("" ::: "memory");
        }
    }
#undef STAGE

    // epilogue ------------------------------------------------------------
    __syncthreads();                   // all ds_reads done; reuse LDS
    float* red = (float*)lds;          // 2 x 256 floats: [wc][256 rows]

    #pragma unroll
    for (int i = 0; i < 4; ++i)
        #pragma unroll
        for (int r = 0; r < 4; ++r) {
            float s = __expf(acc[i][0][r] * INV_TEMP)
                    + __expf(acc[i][1][r] * INV_TEMP)
                    + __expf(acc[i][2][r] * INV_TEMP)
                    + __expf(acc[i][3][r] * INV_TEMP);
            s += __shfl_xor(s, 1);
            s += __shfl_xor(s, 2);
            s += __shfl_xor(s, 4);
            s += __shfl_xor(s, 8);
            if (l16 == 0)
                red[wc * 256 + wr * 64 + i * 16 + quad * 4 + r] = s;
        }
    __syncthreads();

    if (tid < 256)
        part[(size_t)colblk * NROWS + rowbase + tid] = red[tid] + red[256 + tid];
}

// ---------------------------------------------------------------------------
// Kernel 3: per-row total + log - diag, block partials, fused final mean via
// a 64-block completion ticket (64 agent-scope RMWs, us-scale — R6-proven).
// ---------------------------------------------------------------------------
__global__ __launch_bounds__(128) void rowsum_final_kernel(
    const float* __restrict__ part, const float* __restrict__ diag,
    float* __restrict__ loss_part, int* __restrict__ tickets,
    float* __restrict__ out)
{
    const int row = blockIdx.x * 128 + threadIdx.x;
    float s = 0.0f;
    #pragma unroll 4
    for (int cb = 0; cb < 64; ++cb)
        s += part[(size_t)cb * NROWS + row];     // coalesced across threads
    float v = logf(s) - diag[row];

    #pragma unroll
    for (int m = 1; m < 64; m <<= 1) v += __shfl_xor(v, m);
    __shared__ float wsum[2];
    __shared__ int swin;
    if ((threadIdx.x & 63) == 0) wsum[threadIdx.x >> 6] = v;
    __syncthreads();
    if (threadIdx.x == 0) {
        __hip_atomic_store(&loss_part[blockIdx.x], wsum[0] + wsum[1],
            __ATOMIC_RELEASE, __HIP_MEMORY_SCOPE_AGENT);
        swin = __hip_atomic_fetch_add(&tickets[0], 1,
                   __ATOMIC_ACQ_REL, __HIP_MEMORY_SCOPE_AGENT);
    }
    __syncthreads();
    if (swin != 63) return;            // not the last block

    if (threadIdx.x < 64) {
        float x = __hip_atomic_load(&loss_part[threadIdx.x],
                      __ATOMIC_RELAXED, __HIP_MEMORY_SCOPE_AGENT);
        #pragma unroll
        for (int m = 1; m < 64; m <<= 1) x += __shfl_xor(x, m);
        if (threadIdx.x == 0) out[0] = x * (1.0f / NROWS);
    }
}

// ---------------------------------------------------------------------------
extern "C" void kernel_launch(void* const* d_in, const int* in_sizes, int n_in,
                              void* d_out, int out_size, void* d_ws, size_t ws_size,
                              hipStream_t stream)
{
    const float* q = (const float*)d_in[0];
    const float* p = (const float*)d_in[1];

    char* ws = (char*)d_ws;
    unsigned short* qn   = (unsigned short*)ws;                          // 4 MB
    unsigned short* pn   = (unsigned short*)(ws + (size_t)NROWS*DDIM*2); // 4 MB
    float* part      = (float*)(ws + 2*(size_t)NROWS*DDIM*2);            // 2 MB
    float* diag      = part + 64 * (size_t)NROWS;                        // 32 KB
    float* loss_part = diag + NROWS;                                     // 256 B
    int*   tickets   = (int*)(loss_part + 64);

    norm_diag_kernel<<<NROWS/4, 256, 0, stream>>>(q, p, qn, pn, diag, tickets);

    simexp_kernel<<<2048, 512, 0, stream>>>(qn, pn, part);

    rowsum_final_kernel<<<64, 128, 0, stream>>>(part, diag, loss_part,
                                                tickets, (float*)d_out);
}